// Round 2
// baseline (433.715 us; speedup 1.0000x reference)
//
#include <hip/hip_runtime.h>
#include <hip/hip_bf16.h>
#include <cstdint>
#include <cstddef>

#define DEVI __device__ __forceinline__

typedef unsigned short u16;
using frag_ab = __attribute__((ext_vector_type(8))) short;   // 8 bf16 (4 VGPRs)
using f32x4   = __attribute__((ext_vector_type(4))) float;   // mfma acc

constexpr int HW = 16384;   // 128*128 spatial
constexpr int NC = 256;     // channels (Cin = Cout = 256)

DEVI u16 bf16bits(float f) {
    union { float f; uint32_t u; } cv; cv.f = f;
    uint32_t u = cv.u;
    u += 0x7fffu + ((u >> 16) & 1u);   // RNE
    return (u16)(u >> 16);
}

DEVI void gload16(const void* g, void* l) {
    __builtin_amdgcn_global_load_lds(
        (const __attribute__((address_space(1))) uint32_t*)g,
        (__attribute__((address_space(3))) uint32_t*)l, 16, 0, 0);
}

// LDS slab layout: [row][64B k-slice]; 16B slot s stored at phys slot s ^ (row&3) ^ ((row>>2)&3)
// -> ds_read_b128 frag loads are 2-way bank-aliased (free, m136), staging stays gload16-linear
// (pre-swizzled global source, m173).
DEVI frag_ab read_frag(const u16* slab, int row, int l4) {
    const int phys = (l4 ^ row ^ (row >> 2)) & 3;
    return *(const frag_ab*)((const char*)slab + row * 64 + phys * 16);
}

// ---------------- pass 1: x partial stats + transpose to xt[b][p][c] bf16 ----------------
// partials: ps/pq[b][pblk][c] (pblk = 64-pixel slice), non-atomic, coalesced
__global__ __launch_bounds__(256) void transpose_stats_kernel(
    const float* __restrict__ x, u16* __restrict__ xt,
    float* __restrict__ ps, float* __restrict__ pq)
{
    __shared__ __align__(16) u16 tile[64][72];   // [p][c], pad 72 keeps rows 16B-multiple
    const int b = blockIdx.z, c0 = blockIdx.y * 64, p0 = blockIdx.x * 64;
    const int pblk = blockIdx.x;                 // 0..255
    const int t = threadIdx.x;
    const int f = t & 15, cw = t >> 4;
    const float* xb = x + ((size_t)b * NC + c0) * HW + p0;
    #pragma unroll
    for (int pass = 0; pass < 4; ++pass) {
        const int cl = cw + pass * 16;
        const float4 v = *(const float4*)(xb + (size_t)cl * HW + f * 4);
        float s1 = v.x + v.y + v.z + v.w;
        float s2 = v.x*v.x + v.y*v.y + v.z*v.z + v.w*v.w;
        #pragma unroll
        for (int d = 1; d < 16; d <<= 1) {
            s1 += __shfl_xor(s1, d, 64);
            s2 += __shfl_xor(s2, d, 64);
        }
        if (f == 0) {
            ps[((size_t)b * 256 + pblk) * NC + c0 + cl] = s1;
            pq[((size_t)b * 256 + pblk) * NC + c0 + cl] = s2;
        }
        tile[f*4+0][cl] = bf16bits(v.x);
        tile[f*4+1][cl] = bf16bits(v.y);
        tile[f*4+2][cl] = bf16bits(v.z);
        tile[f*4+3][cl] = bf16bits(v.w);
    }
    __syncthreads();
    const int pl = t >> 2, q = t & 3;
    u16* dst = xt + ((size_t)b * HW + p0 + pl) * NC + c0;
    #pragma unroll
    for (int s = 0; s < 2; ++s) {
        const int ch = q + s * 4;
        *(uint4*)(dst + ch * 8) = *(const uint4*)(&tile[pl][ch * 8]);
    }
}

// ---------------- fold: reduce partials -> mu/rs, fold IN into weights/bias ----------------
// we[b][o][c] = w[o][c]*rs[b][c] (bf16), be[b][o] = bias[o] - sum_c w[o][c]*mu[b][c]*rs[b][c]
__global__ __launch_bounds__(256) void fold_kernel(
    const float* __restrict__ w, const float* __restrict__ bias,
    const float* __restrict__ ps, const float* __restrict__ pq, int P,
    u16* __restrict__ we, float* __restrict__ be)
{
    const int b = blockIdx.y, oc = blockIdx.x * 64;
    __shared__ float mu[NC], rs[NC];
    __shared__ __align__(16) float wt[64 * NC];
    const int t = threadIdx.x;
    {
        float s1 = 0.f, s2 = 0.f;
        const float* pp = ps + (size_t)b * P * NC + t;
        const float* qq = pq + (size_t)b * P * NC + t;
        for (int i = 0; i < P; ++i) { s1 += pp[(size_t)i * NC]; s2 += qq[(size_t)i * NC]; }
        const float m = s1 * (1.0f / HW);
        mu[t] = m;
        rs[t] = rsqrtf(s2 * (1.0f / HW) - m * m + 1e-5f);
    }
    #pragma unroll
    for (int i = 0; i < 16; ++i)
        *(float4*)&wt[i*1024 + t*4] = *(const float4*)&w[(size_t)oc*NC + i*1024 + t*4];
    __syncthreads();
    const int o = oc + (t >> 2), q = t & 3;
    const float* wrow = &wt[(t >> 2) * NC];
    u16* werow = we + ((size_t)b * NC + o) * NC;
    float bacc = 0.f;
    for (int cc = 0; cc < 8; ++cc) {
        alignas(16) u16 pk[8];
        #pragma unroll
        for (int jj = 0; jj < 8; ++jj) {
            const int c = q*64 + cc*8 + jj;
            const float wv = wrow[c];
            bacc -= wv * mu[c] * rs[c];
            pk[jj] = bf16bits(wv * rs[c]);
        }
        *(uint4*)(werow + q*64 + cc*8) = *(const uint4*)pk;
    }
    bacc += __shfl_xor(bacc, 1, 64);
    bacc += __shfl_xor(bacc, 2, 64);
    if (q == 0) be[b*NC + o] = bias[o] + bacc;
}

// ---------------- fused GEMM, 128x128 tile (m97 structure) ----------------
// STAGE1: D[p][o] = relu(xt[p][:] . w1e[o][:] + b1e[o]) -> ht[b][p][o] bf16, + h col-sum partials
// STAGE2: D[o][p] = relu(w2e[o][:] . ht[p][:] + b2e[o]) -> out[b][o][p] fp32 (native NCHW)
template<int STAGE>
__global__ __launch_bounds__(256, 3) void gemm_kernel(
    const u16* __restrict__ pixM,   // pixel matrix [B*HW][NC] (xt or ht)
    const u16* __restrict__ wMat,   // folded weights [B][NC][NC]
    const float* __restrict__ biasE,// [B][NC]
    u16* __restrict__ outB,         // stage1: ht
    float* __restrict__ outF,       // stage2: out
    float* __restrict__ hps, float* __restrict__ hpq)  // stage1 partials [b][ptile][o]
{
    __shared__ __align__(16) u16 ldsP[128 * 32];   // pixel slab: 128 rows x 32 bf16
    __shared__ __align__(16) u16 ldsW[128 * 32];   // weight slab: 128 rows x 32 bf16
    __shared__ float red1[4][64], red2[4][64];

    const int b  = blockIdx.z;
    const int o0 = blockIdx.y * 128;
    const int p0 = blockIdx.x * 128;
    const int tid = threadIdx.x;
    const int lane = tid & 63, wid = tid >> 6;
    const int wr = wid >> 1, wc = wid & 1;
    const int l15 = lane & 15, l4 = lane >> 4;

    const u16* gP = pixM + ((size_t)b * HW + p0) * NC;
    const u16* gW = wMat + ((size_t)b * NC + o0) * NC;

    f32x4 acc[4][4];
    #pragma unroll
    for (int i = 0; i < 4; ++i)
        #pragma unroll
        for (int j = 0; j < 4; ++j)
            acc[i][j] = (f32x4){0.f, 0.f, 0.f, 0.f};

    const int rin  = lane >> 2;                    // staging row within 16-row chunk
    const int ssrc = ((lane & 3) ^ ((lane >> 2) & 3) ^ ((lane >> 4) & 3));  // pre-swizzled slot

    for (int ks = 0; ks < 8; ++ks) {
        const int k0 = ks * 32;
        #pragma unroll
        for (int j = wid; j < 16; j += 4) {
            if (j < 8) {
                const int row = j * 16 + rin;
                gload16(gW + (size_t)row * NC + k0 + ssrc * 8, (char*)ldsW + j * 1024);
            } else {
                const int row = (j - 8) * 16 + rin;
                gload16(gP + (size_t)row * NC + k0 + ssrc * 8, (char*)ldsP + (j - 8) * 1024);
            }
        }
        __syncthreads();

        const u16* slabA; const u16* slabB;
        if constexpr (STAGE == 1) { slabA = ldsP; slabB = ldsW; }
        else                      { slabA = ldsW; slabB = ldsP; }
        const int aOff = 64 * wr, bOff = 64 * wc;

        frag_ab a[4];
        #pragma unroll
        for (int mi = 0; mi < 4; ++mi)
            a[mi] = read_frag(slabA, aOff + 16*mi + l15, l4);
        #pragma unroll
        for (int ni = 0; ni < 4; ++ni) {
            const frag_ab bfr = read_frag(slabB, bOff + 16*ni + l15, l4);
            #pragma unroll
            for (int mi = 0; mi < 4; ++mi)
                acc[mi][ni] = __builtin_amdgcn_mfma_f32_16x16x32_bf16(a[mi], bfr, acc[mi][ni], 0, 0, 0);
        }
        __syncthreads();
    }

    if constexpr (STAGE == 1) {
        // rows = pixels (wr half), cols = outputs (wc half)
        u16* htp = outB + ((size_t)b * HW + p0 + wr*64) * NC + o0 + wc*64;
        #pragma unroll
        for (int ni = 0; ni < 4; ++ni) {
            const int ocol = o0 + wc*64 + 16*ni + l15;
            const float bn = biasE[b*NC + ocol];
            float s1 = 0.f, s2 = 0.f;
            #pragma unroll
            for (int mi = 0; mi < 4; ++mi) {
                #pragma unroll
                for (int r = 0; r < 4; ++r) {
                    const float v = fmaxf(acc[mi][ni][r] + bn, 0.f);
                    s1 += v; s2 += v * v;
                    htp[(size_t)(16*mi + l4*4 + r) * NC + 16*ni + l15] = bf16bits(v);
                }
            }
            s1 += __shfl_xor(s1, 16, 64); s1 += __shfl_xor(s1, 32, 64);
            s2 += __shfl_xor(s2, 16, 64); s2 += __shfl_xor(s2, 32, 64);
            if (lane < 16) { red1[wid][ni*16 + lane] = s1; red2[wid][ni*16 + lane] = s2; }
        }
        __syncthreads();
        if (tid < 128) {
            const int wcc = tid >> 6, ci = tid & 63;
            const float s1 = red1[wcc][ci] + red1[2 + wcc][ci];
            const float s2 = red2[wcc][ci] + red2[2 + wcc][ci];
            hps[((size_t)b * 128 + blockIdx.x) * NC + o0 + tid] = s1;
            hpq[((size_t)b * 128 + blockIdx.x) * NC + o0 + tid] = s2;
        }
    } else {
        // rows = outputs (wr half), cols = pixels (wc half) -> native NCHW
        float* op = outF + ((size_t)b * NC + o0 + wr*64) * HW + p0 + wc*64;
        #pragma unroll
        for (int mi = 0; mi < 4; ++mi) {
            #pragma unroll
            for (int r = 0; r < 4; ++r) {
                const int orow = 16*mi + l4*4 + r;
                const float bm = biasE[b*NC + o0 + wr*64 + orow];
                #pragma unroll
                for (int ni = 0; ni < 4; ++ni)
                    op[(size_t)orow * HW + 16*ni + l15] = fmaxf(acc[mi][ni][r] + bm, 0.f);
            }
        }
    }
}

extern "C" void kernel_launch(void* const* d_in, const int* in_sizes, int n_in,
                              void* d_out, int out_size, void* d_ws, size_t ws_size,
                              hipStream_t stream)
{
    (void)in_sizes; (void)n_in; (void)out_size;
    const float* x  = (const float*)d_in[0];
    const float* w1 = (const float*)d_in[1];
    const float* b1 = (const float*)d_in[2];
    const float* w2 = (const float*)d_in[3];
    const float* b2 = (const float*)d_in[4];
    float* out = (float*)d_out;

    // scratch carved out of d_out (268 MB): everything here is dead before gemm<2> overwrites it
    char* od = (char*)d_out;
    u16*   xt  = (u16*)od;                        // 134,217,728 B
    float* xps = (float*)(od + 134217728);        //   4,194,304 (16*256*256 f32)
    float* xpq = (float*)(od + 138412032);        //   4,194,304
    float* hps = (float*)(od + 142606336);        //   2,097,152 (16*128*256 f32)
    float* hpq = (float*)(od + 144703488);        //   2,097,152

    char* ws = (char*)d_ws;
    const size_t NEED = 138444800;
    if (ws_size < NEED) return;                   // loud failure instead of corruption
    u16*   ht  = (u16*)(ws);                      // 134,217,728
    u16*   w1e = (u16*)(ws + 134217728);          //   2,097,152
    u16*   w2e = (u16*)(ws + 136314880);          //   2,097,152
    float* b1e = (float*)(ws + 138412032);        //      16,384
    float* b2e = (float*)(ws + 138428416);        //      16,384

    transpose_stats_kernel<<<dim3(HW/64, NC/64, 16), 256, 0, stream>>>(x, xt, xps, xpq);
    fold_kernel<<<dim3(4, 16), 256, 0, stream>>>(w1, b1, xps, xpq, 256, w1e, b1e);
    gemm_kernel<1><<<dim3(HW/128, 2, 16), 256, 0, stream>>>(xt, w1e, b1e, ht, nullptr, hps, hpq);
    fold_kernel<<<dim3(4, 16), 256, 0, stream>>>(w2, b2, hps, hpq, 128, w2e, b2e);
    gemm_kernel<2><<<dim3(HW/128, 2, 16), 256, 0, stream>>>(ht, w2e, b2e, nullptr, out, nullptr, nullptr);
}